// Round 5
// baseline (184.420 us; speedup 1.0000x reference)
//
#include <hip/hip_runtime.h>
#include <hip/hip_bf16.h>
#include <stdint.h>

#define K_TAPS 15
#define CIN    128
#define F_OUT  256
#define LSEQ   4096
#define LOUT   (LSEQ - K_TAPS + 1)   // 4082
#define BATCH  32

typedef __attribute__((ext_vector_type(8))) short bf16x8;
typedef __attribute__((ext_vector_type(16))) float f32x16;

typedef __attribute__((address_space(1))) const unsigned int gu32_t;
typedef __attribute__((address_space(3))) unsigned int su32_t;

// ---------------------------------------------------------------------------
// prep: weights fp32 [k][c][f] -> bf16 Wp, layout [(k*2+chalf)][f][64 ch swz]
// swizzle: within a 64-chan half, granule g=c6>>3 stored at slot g^(f&7)
// (round-3 layout -- staging src contiguous, LDS dest linear)
// ---------------------------------------------------------------------------
__global__ void prep_w_kernel(const float* __restrict__ W,
                              unsigned short* __restrict__ Wp) {
  int idx = blockIdx.x * 256 + threadIdx.x;   // 15*128*256 = 491520 total
  int f  = idx & 255;
  int kc = idx >> 8;
  int c  = kc & 127;
  int k  = kc >> 7;
  float w = W[idx];
  __hip_bfloat16 hb = __float2bfloat16(w);
  int chalf = c >> 6;
  int c6    = c & 63;
  int slot  = ((c6 >> 3) ^ f) & 7;
  int cp    = slot * 8 + (c & 7);
  Wp[((size_t)(k * 2 + chalf) * 256 + f) * 64 + cp] =
      *reinterpret_cast<unsigned short*>(&hb);
}

// ---------------------------------------------------------------------------
// fused main kernel: implicit-GEMM conv (32x32x16 MFMA) + window-norm + bias
// block: 256 thr (4 waves, 2x2 wave grid, 64x64 per wave) -> 128(M)x128(N)
// LDS: Xs [144 rows][128 ch] bf16 swizzled (round-3 swizzle, staged once)
//      Bs double buffer, each [128 f][64 ch swz] (global_load_lds, 16B)
//      sqs[144] per-row sum(x^2) -> rns[128] scale/sqrt(win+eps)
// K loop: 30 phases (tap x chan-half); counted vmcnt(4) dbuf + setprio
// ---------------------------------------------------------------------------
#define BM 128
#define BN 128
#define XROWS 144
#define XBYTES (XROWS * 256)   // 36864
#define BBYTES 16384           // one [128][64] bf16 buffer
#define NPHASE (K_TAPS * 2)    // 30

__global__ __launch_bounds__(256, 2) void conv_gemm_kernel(
    const float* __restrict__ x, const unsigned short* __restrict__ Wp,
    const float* __restrict__ scale, const float* __restrict__ bias,
    float* __restrict__ out)
{
  __shared__ __align__(16) char lds[XBYTES + 2 * BBYTES];  // 69632 B
  __shared__ float sqs[XROWS];
  __shared__ float rns[BM];
  char* Xs = lds;
  char* Bs = lds + XBYTES;

  const int b     = blockIdx.y;
  const int mtile = blockIdx.x >> 1;
  const int ntile = blockIdx.x & 1;
  const int t0    = mtile * BM;
  const int n0    = ntile * BN;

  const int tx   = threadIdx.x;
  const int wid  = tx >> 6;
  const int lane = tx & 63;
  const int wm   = wid >> 1;
  const int wn   = wid & 1;

  const float scalev = scale[0];

  // ---- B staging: one 16 KB half-tap image, linear dest (swz baked in Wp)
  auto stageB = [&](int buf, int phase) {
    const char* src = (const char*)Wp + (size_t)phase * 32768
                      + (size_t)n0 * 128;  // n0*64ch*2B
    char* dst = Bs + buf * BBYTES;
    int base = wid * 4096;
    #pragma unroll
    for (int i = 0; i < 4; ++i) {
      int off = base + i * 1024;
      __builtin_amdgcn_global_load_lds(
          (gu32_t*)(src + off + lane * 16),
          (su32_t*)(dst + off), 16, 0, 0);
    }
  };

  stageB(0, 0);   // overlaps with X staging below; drained by __syncthreads

  // ---- stage X once: 144 rows x 128 ch, fp32 -> bf16, XOR-swizzled;
  //      also reduce sum(x^2) per row into sqs[]
  {
    const int rloc = tx >> 4;    // row within 16-row slab
    const int g    = tx & 15;    // 16B granule (8 chans)
    const float* xb = x + (long)b * LSEQ * CIN;
    #pragma unroll
    for (int it = 0; it < 9; ++it) {
      int row  = it * 16 + rloc;
      int grow = t0 + row;
      float v[8];
      if (grow < LSEQ) {
        const float4* p = (const float4*)(xb + (long)grow * CIN + g * 8);
        float4 a0 = p[0], a1 = p[1];
        v[0]=a0.x; v[1]=a0.y; v[2]=a0.z; v[3]=a0.w;
        v[4]=a1.x; v[5]=a1.y; v[6]=a1.z; v[7]=a1.w;
      } else {
        #pragma unroll
        for (int j = 0; j < 8; ++j) v[j] = 0.f;
      }
      float s = 0.f;
      union { unsigned short us[8]; int4 q; } pk;
      #pragma unroll
      for (int j = 0; j < 8; ++j) {
        s += v[j] * v[j];
        __hip_bfloat16 hb = __float2bfloat16(v[j]);
        pk.us[j] = *reinterpret_cast<unsigned short*>(&hb);
      }
      int slot = (g & 8) | ((g ^ row) & 7);
      *(int4*)(Xs + row * 256 + slot * 16) = pk.q;
      // reduce s over the 16 loader lanes of this row
      s += __shfl_xor(s, 1, 16);
      s += __shfl_xor(s, 2, 16);
      s += __shfl_xor(s, 4, 16);
      s += __shfl_xor(s, 8, 16);
      if (g == 0) sqs[row] = s;
    }
  }
  __syncthreads();   // X + sqs ready, stage(0) drained; vmcnt=0 at loop entry

  // ---- window norm: rns[t] = scale / sqrt(sum_{k<15} sqs[t+k] + eps)
  if (tx < BM) {
    float wsum = 0.f;
    #pragma unroll
    for (int k = 0; k < K_TAPS; ++k) wsum += sqs[tx + k];
    rns[tx] = scalev / sqrtf(wsum + 1e-7f);
  }

  // acc[parity][wfm][wfn]: K-step-parity split keeps acc-reuse distance at 8
  f32x16 acc[2][2][2] = {};

  const int l31   = lane & 31;
  const int khalf = lane >> 5;
  const int arow0 = wm * 64;
  const int bcol0 = wn * 64;

  #pragma unroll 2
  for (int ph = 0; ph < NPHASE; ++ph) {
    const int buf    = ph & 1;
    const int tap    = ph >> 1;
    const int chalf8 = (ph & 1) * 8;   // global granule base of this half-tap

    // issue next-phase B prefetch (stays in flight across the barrier)
    if (ph + 1 < NPHASE) stageB(buf ^ 1, ph + 1);

    // hoist all 8 A ds_reads -- Xs is immutable, no barrier needed
    bf16x8 af[4][2];   // [K-step s][wfm]
    #pragma unroll
    for (int s = 0; s < 4; ++s) {
      const int ga = chalf8 + 2 * s + khalf;   // granule 0..15
      #pragma unroll
      for (int wfm = 0; wfm < 2; ++wfm) {
        int row  = arow0 + wfm * 32 + l31 + tap;
        int slot = (ga & 8) | ((ga ^ row) & 7);
        af[s][wfm] = *(const bf16x8*)(Xs + row * 256 + slot * 16);
      }
    }

    // counted wait: drain only THIS phase's B loads, keep next 4 in flight
    if (ph + 1 < NPHASE) {
      asm volatile("s_waitcnt vmcnt(4)" ::: "memory");
    } else {
      asm volatile("s_waitcnt vmcnt(0)" ::: "memory");
    }
    __builtin_amdgcn_s_barrier();      // buf(ph) ready in all waves

    const char* Bsc = Bs + buf * BBYTES;
    bf16x8 bfr[4][2];  // [K-step s][wfn]
    #pragma unroll
    for (int s = 0; s < 4; ++s) {
      const int gb = 2 * s + khalf;    // granule within the 64-chan half
      #pragma unroll
      for (int wfn = 0; wfn < 2; ++wfn) {
        int fc   = bcol0 + wfn * 32 + l31;
        int slot = (gb ^ fc) & 7;
        bfr[s][wfn] = *(const bf16x8*)(Bsc + fc * 128 + slot * 16);
      }
    }

    __builtin_amdgcn_s_setprio(1);
    #pragma unroll
    for (int s = 0; s < 4; ++s)
      #pragma unroll
      for (int wfm = 0; wfm < 2; ++wfm)
        #pragma unroll
        for (int wfn = 0; wfn < 2; ++wfn)
          acc[s & 1][wfm][wfn] = __builtin_amdgcn_mfma_f32_32x32x16_bf16(
              af[s][wfm], bfr[s][wfn], acc[s & 1][wfm][wfn], 0, 0, 0);
    __builtin_amdgcn_s_setprio(0);

    // buf's ds_reads complete before next phase's stage may overwrite it
    asm volatile("s_waitcnt lgkmcnt(0)" ::: "memory");
    __builtin_amdgcn_s_barrier();
  }

  // ---- epilogue: out = acc * rns[row] + bias[f]
  // 32x32 C/D layout: col = lane&31, row = (reg&3) + 8*(reg>>2) + 4*(lane>>5)
  float* ob = out + (long)b * LOUT * F_OUT;
  float biasv[2];
  #pragma unroll
  for (int wfn = 0; wfn < 2; ++wfn)
    biasv[wfn] = bias[n0 + bcol0 + wfn * 32 + l31];
  #pragma unroll
  for (int wfm = 0; wfm < 2; ++wfm) {
    #pragma unroll
    for (int reg = 0; reg < 16; ++reg) {
      int rloc = arow0 + wfm * 32 + (reg & 3) + 8 * (reg >> 2) + 4 * khalf;
      int gt   = t0 + rloc;
      if (gt < LOUT) {
        float rv = rns[rloc];
        #pragma unroll
        for (int wfn = 0; wfn < 2; ++wfn) {
          float v = acc[0][wfm][wfn][reg] + acc[1][wfm][wfn][reg];
          ob[(long)gt * F_OUT + n0 + bcol0 + wfn * 32 + l31] =
              v * rv + biasv[wfn];
        }
      }
    }
  }
}

// ---------------------------------------------------------------------------
extern "C" void kernel_launch(void* const* d_in, const int* in_sizes, int n_in,
                              void* d_out, int out_size, void* d_ws, size_t ws_size,
                              hipStream_t stream) {
  const float* x     = (const float*)d_in[0];   // (32, 4096, 128)
  const float* W     = (const float*)d_in[1];   // (15, 128, 256)
  const float* scale = (const float*)d_in[2];   // (1,1,1)
  const float* bias  = (const float*)d_in[3];   // (256,)
  float* out = (float*)d_out;                   // (32, 4082, 256)

  unsigned short* Wp = (unsigned short*)d_ws;   // 983040 B

  prep_w_kernel<<<1920, 256, 0, stream>>>(W, Wp);
  conv_gemm_kernel<<<dim3(64, BATCH), 256, 0, stream>>>(x, Wp, scale, bias, out);
}

// Round 6
// 156.424 us; speedup vs baseline: 1.1790x; 1.1790x over previous
//
#include <hip/hip_runtime.h>
#include <hip/hip_bf16.h>
#include <stdint.h>

#define K_TAPS 15
#define CIN    128
#define F_OUT  256
#define LSEQ   4096
#define LOUT   (LSEQ - K_TAPS + 1)   // 4082
#define BATCH  32

typedef __attribute__((ext_vector_type(8))) short bf16x8;
typedef __attribute__((ext_vector_type(4))) float f32x4;

typedef __attribute__((address_space(1))) const unsigned int gu32_t;
typedef __attribute__((address_space(3))) unsigned int su32_t;

// ---------------------------------------------------------------------------
// prep: weights fp32 [k][c][f] -> bf16 Wp, layout [(k*2+chalf)][f][64 ch swz]
// swizzle: within a 64-chan half, granule g=c6>>3 stored at slot g^(f&7)
// (round-3 layout -- staging src contiguous, LDS dest linear)
// ---------------------------------------------------------------------------
__global__ void prep_w_kernel(const float* __restrict__ W,
                              unsigned short* __restrict__ Wp) {
  int idx = blockIdx.x * 256 + threadIdx.x;   // 15*128*256 = 491520 total
  int f  = idx & 255;
  int kc = idx >> 8;
  int c  = kc & 127;
  int k  = kc >> 7;
  float w = W[idx];
  __hip_bfloat16 hb = __float2bfloat16(w);
  int chalf = c >> 6;
  int c6    = c & 63;
  int slot  = ((c6 >> 3) ^ f) & 7;
  int cp    = slot * 8 + (c & 7);
  Wp[((size_t)(k * 2 + chalf) * 256 + f) * 64 + cp] =
      *reinterpret_cast<unsigned short*>(&hb);
}

// ---------------------------------------------------------------------------
// fused main kernel: implicit-GEMM conv + window-norm + scale/bias
// block: 512 thr = 8 waves, wave grid 2(M)x4(N), wave tile 128x64
//        -> block tile 256(M) x 256(N);  grid = 16 mtiles x 32 batch
// LDS: Xs [272 rows][128 ch] bf16, round-3 XOR swizzle, staged once
//      Bs double buffer, each [256 f][64 ch swz] (global_load_lds, 16B)
//      sqs[272] per-row sum(x^2) -> rns[256]
// K loop: 30 phases (tap x chan-half); counted vmcnt(4) dbuf + setprio
// reads/MFMA = 24/64 = 0.375 (vs 0.5 at 64x64 wave tile) -> MFMA-bound
// ---------------------------------------------------------------------------
#define BM 256
#define BN 256
#define XROWS 272              // 256 + 15, padded
#define XBYTES (XROWS * 256)   // 69632
#define BBYTES 32768           // one [256][64] bf16 buffer
#define NPHASE (K_TAPS * 2)    // 30

__global__ __launch_bounds__(512, 2) void conv_gemm_kernel(
    const float* __restrict__ x, const unsigned short* __restrict__ Wp,
    const float* __restrict__ scale, const float* __restrict__ bias,
    float* __restrict__ out)
{
  __shared__ __align__(16) char lds[XBYTES + 2 * BBYTES];  // 135168 B
  __shared__ float sqs[XROWS];
  __shared__ float rns[BM];
  char* Xs = lds;
  char* Bs = lds + XBYTES;

  const int b  = blockIdx.y;
  const int t0 = blockIdx.x * BM;

  const int tx   = threadIdx.x;
  const int wid  = tx >> 6;
  const int lane = tx & 63;
  const int wm   = wid >> 2;     // 0..1
  const int wn   = wid & 3;      // 0..3

  const float scalev = scale[0];

  // ---- B staging: one 32 KB half-tap image (all 256 f), linear copy
  auto stageB = [&](int buf, int phase) {
    const char* src = (const char*)Wp + (size_t)phase * 32768;
    char* dst = Bs + buf * BBYTES;
    #pragma unroll
    for (int i = 0; i < 4; ++i) {
      int off = i * 8192 + wid * 1024;   // wave-uniform base
      __builtin_amdgcn_global_load_lds(
          (gu32_t*)(src + off + lane * 16),
          (su32_t*)(dst + off), 16, 0, 0);
    }
  };

  stageB(0, 0);   // overlaps with X staging below; drained by __syncthreads

  // ---- stage X once: 272 rows x 128 ch, fp32 -> bf16, XOR-swizzled;
  //      also reduce sum(x^2) per row into sqs[]
  {
    const int rloc = tx >> 4;    // 0..31, row within 32-row slab
    const int g    = tx & 15;    // 16B granule (8 chans)
    const float* xb = x + (long)b * LSEQ * CIN;
    #pragma unroll
    for (int it = 0; it < 9; ++it) {
      int row  = it * 32 + rloc;          // 0..287
      int grow = t0 + row;
      if (row < XROWS) {
        float v[8];
        if (grow < LSEQ) {
          const float4* p = (const float4*)(xb + (long)grow * CIN + g * 8);
          float4 a0 = p[0], a1 = p[1];
          v[0]=a0.x; v[1]=a0.y; v[2]=a0.z; v[3]=a0.w;
          v[4]=a1.x; v[5]=a1.y; v[6]=a1.z; v[7]=a1.w;
        } else {
          #pragma unroll
          for (int j = 0; j < 8; ++j) v[j] = 0.f;
        }
        float s = 0.f;
        union { unsigned short us[8]; int4 q; } pk;
        #pragma unroll
        for (int j = 0; j < 8; ++j) {
          s += v[j] * v[j];
          __hip_bfloat16 hb = __float2bfloat16(v[j]);
          pk.us[j] = *reinterpret_cast<unsigned short*>(&hb);
        }
        int slot = (g & 8) | ((g ^ row) & 7);
        *(int4*)(Xs + row * 256 + slot * 16) = pk.q;
        // reduce s over the 16 loader lanes of this row
        s += __shfl_xor(s, 1, 16);
        s += __shfl_xor(s, 2, 16);
        s += __shfl_xor(s, 4, 16);
        s += __shfl_xor(s, 8, 16);
        if (g == 0) sqs[row] = s;
      }
    }
  }
  __syncthreads();   // X + sqs ready, stage(0) drained; vmcnt=0 at loop entry

  // ---- window norm: rns[t] = scale / sqrt(sum_{k<15} sqs[t+k] + eps)
  if (tx < BM) {
    float wsum = 0.f;
    #pragma unroll
    for (int k = 0; k < K_TAPS; ++k) wsum += sqs[tx + k];
    rns[tx] = scalev / sqrtf(wsum + 1e-7f);
  }

  f32x4 acc[8][4] = {};   // [mf][nf], wave tile 128x64

  const int klane = lane >> 4;
  const int rl    = lane & 15;
  const int arow0 = wm * 128;
  const int bcol0 = wn * 64;

  #pragma unroll 2
  for (int ph = 0; ph < NPHASE; ++ph) {
    const int buf = ph & 1;
    const int tap = ph >> 1;
    const int kk0 = (ph & 1) * 2;

    // issue next-phase B prefetch (stays in flight across the barrier)
    if (ph + 1 < NPHASE) stageB(buf ^ 1, ph + 1);

    // hoist all 16 A ds_reads -- Xs is immutable, no barrier needed
    bf16x8 af[2][8];
    #pragma unroll
    for (int j = 0; j < 2; ++j) {
      const int ga = (kk0 + j) * 4 + klane;   // A granule 0..15
      #pragma unroll
      for (int mf = 0; mf < 8; ++mf) {
        int row  = arow0 + mf * 16 + rl + tap;
        int slot = (ga & 8) | ((ga ^ row) & 7);
        af[j][mf] = *(const bf16x8*)(Xs + row * 256 + slot * 16);
      }
    }

    // counted wait: drain only THIS phase's B loads, keep next 4 in flight
    if (ph + 1 < NPHASE) {
      asm volatile("s_waitcnt vmcnt(4)" ::: "memory");
    } else {
      asm volatile("s_waitcnt vmcnt(0)" ::: "memory");
    }
    __builtin_amdgcn_s_barrier();      // buf(ph) ready in all waves

    const char* Bsc = Bs + buf * BBYTES;
    #pragma unroll
    for (int j = 0; j < 2; ++j) {
      const int gb = ((kk0 + j) & 1) * 4 + klane;  // granule within half
      bf16x8 bfr[4];
      #pragma unroll
      for (int nf = 0; nf < 4; ++nf) {
        int fc   = bcol0 + nf * 16 + rl;
        int slot = (gb ^ fc) & 7;
        bfr[nf] = *(const bf16x8*)(Bsc + fc * 128 + slot * 16);
      }
      __builtin_amdgcn_s_setprio(1);
      #pragma unroll
      for (int mf = 0; mf < 8; ++mf)
        #pragma unroll
        for (int nf = 0; nf < 4; ++nf)
          acc[mf][nf] = __builtin_amdgcn_mfma_f32_16x16x32_bf16(
              af[j][mf], bfr[nf], acc[mf][nf], 0, 0, 0);
      __builtin_amdgcn_s_setprio(0);
    }

    // buf's ds_reads complete before next phase's stage may overwrite it
    asm volatile("s_waitcnt lgkmcnt(0)" ::: "memory");
    __builtin_amdgcn_s_barrier();
  }

  // ---- epilogue: out = acc * rns[row] + bias[f]
  // C/D layout: col = lane&15, row = (lane>>4)*4 + reg  [m89-verified]
  const int rgrp = lane >> 4;
  float biasv[4];
  #pragma unroll
  for (int nf = 0; nf < 4; ++nf) biasv[nf] = bias[bcol0 + nf * 16 + rl];
  float* ob = out + (long)b * LOUT * F_OUT;
  #pragma unroll
  for (int mf = 0; mf < 8; ++mf) {
    #pragma unroll
    for (int r = 0; r < 4; ++r) {
      int row = arow0 + mf * 16 + rgrp * 4 + r;
      int gt  = t0 + row;
      if (gt < LOUT) {
        float rv = rns[row];
        #pragma unroll
        for (int nf = 0; nf < 4; ++nf) {
          ob[(long)gt * F_OUT + bcol0 + nf * 16 + rl] =
              acc[mf][nf][r] * rv + biasv[nf];
        }
      }
    }
  }
}

// ---------------------------------------------------------------------------
extern "C" void kernel_launch(void* const* d_in, const int* in_sizes, int n_in,
                              void* d_out, int out_size, void* d_ws, size_t ws_size,
                              hipStream_t stream) {
  const float* x     = (const float*)d_in[0];   // (32, 4096, 128)
  const float* W     = (const float*)d_in[1];   // (15, 128, 256)
  const float* scale = (const float*)d_in[2];   // (1,1,1)
  const float* bias  = (const float*)d_in[3];   // (256,)
  float* out = (float*)d_out;                   // (32, 4082, 256)

  unsigned short* Wp = (unsigned short*)d_ws;   // 983040 B

  prep_w_kernel<<<1920, 256, 0, stream>>>(W, Wp);
  conv_gemm_kernel<<<dim3(16, BATCH), 512, 0, stream>>>(x, Wp, scale, bias, out);
}

// Round 7
// 155.489 us; speedup vs baseline: 1.1861x; 1.0060x over previous
//
#include <hip/hip_runtime.h>
#include <hip/hip_bf16.h>
#include <stdint.h>

#define K_TAPS 15
#define CIN    128
#define F_OUT  256
#define LSEQ   4096
#define LOUT   (LSEQ - K_TAPS + 1)   // 4082
#define BATCH  32

typedef __attribute__((ext_vector_type(8))) short bf16x8;
typedef __attribute__((ext_vector_type(4))) float f32x4;

typedef __attribute__((address_space(1))) const unsigned int gu32_t;
typedef __attribute__((address_space(3))) unsigned int su32_t;

// ---------------------------------------------------------------------------
// prep: weights fp32 [k][c][f] -> bf16 Wp, layout [(k*2+chalf)][f][64 ch swz]
// swizzle: within a 64-chan half, granule g=c6>>3 stored at slot g^(f&7)
// (round-3 layout -- staging src contiguous, LDS dest linear)
// ---------------------------------------------------------------------------
__global__ void prep_w_kernel(const float* __restrict__ W,
                              unsigned short* __restrict__ Wp) {
  int idx = blockIdx.x * 256 + threadIdx.x;   // 15*128*256 = 491520 total
  int f  = idx & 255;
  int kc = idx >> 8;
  int c  = kc & 127;
  int k  = kc >> 7;
  float w = W[idx];
  __hip_bfloat16 hb = __float2bfloat16(w);
  int chalf = c >> 6;
  int c6    = c & 63;
  int slot  = ((c6 >> 3) ^ f) & 7;
  int cp    = slot * 8 + (c & 7);
  Wp[((size_t)(k * 2 + chalf) * 256 + f) * 64 + cp] =
      *reinterpret_cast<unsigned short*>(&hb);
}

// ---------------------------------------------------------------------------
// fused main kernel: implicit-GEMM conv + window-norm + scale/bias
// R3-exact GEMM structure (133.5 us verified):
//   block: 256 thr (4 waves, 2x2 wave grid, 64x64 per wave) -> 128M x 128N
//   LDS: Xs [144 rows][128 ch] bf16 swizzled (staged once)
//        Bs double buffer, each [128 f][64 ch swz] (global_load_lds, 16B)
//   30 phases; counted vmcnt(4) double buffer + setprio
// Fused (R4-proven, orthogonal): sqs[144] sum(x^2) during staging -> rns[128]
// ---------------------------------------------------------------------------
#define BM 128
#define BN 128
#define XROWS 144
#define XBYTES (XROWS * 256)   // 36864
#define BBYTES 16384           // one [128][64] bf16 buffer
#define NPHASE (K_TAPS * 2)    // 30

__global__ __launch_bounds__(256, 2) void conv_gemm_kernel(
    const float* __restrict__ x, const unsigned short* __restrict__ Wp,
    const float* __restrict__ scale, const float* __restrict__ bias,
    float* __restrict__ out)
{
  __shared__ __align__(16) char lds[XBYTES + 2 * BBYTES];  // 69632 B
  __shared__ float sqs[XROWS];
  __shared__ float rns[BM];
  char* Xs = lds;
  char* Bs = lds + XBYTES;

  const int b     = blockIdx.y;
  const int mtile = blockIdx.x >> 1;
  const int ntile = blockIdx.x & 1;
  const int t0    = mtile * BM;
  const int n0    = ntile * BN;

  const int tx   = threadIdx.x;
  const int wid  = tx >> 6;
  const int lane = tx & 63;
  const int wm   = wid >> 1;
  const int wn   = wid & 1;

  const float scalev = scale[0];

  // ---- B staging: one 16 KB half-tap image, linear dest (swz baked in Wp)
  auto stageB = [&](int buf, int phase) {
    const char* src = (const char*)Wp + (size_t)phase * 32768
                      + (size_t)n0 * 128;  // n0*64ch*2B
    char* dst = Bs + buf * BBYTES;
    int base = wid * 4096;
    #pragma unroll
    for (int i = 0; i < 4; ++i) {
      int off = base + i * 1024;
      __builtin_amdgcn_global_load_lds(
          (gu32_t*)(src + off + lane * 16),
          (su32_t*)(dst + off), 16, 0, 0);
    }
  };

  stageB(0, 0);   // overlaps with X staging below; drained by __syncthreads

  // ---- stage X once: 144 rows x 128 ch, fp32 -> bf16, XOR-swizzled;
  //      also reduce sum(x^2) per row into sqs[] (fused sq)
  {
    const int rloc = tx >> 4;    // row within 16-row slab
    const int g    = tx & 15;    // 16B granule (8 chans)
    const float* xb = x + (long)b * LSEQ * CIN;
    #pragma unroll
    for (int it = 0; it < 9; ++it) {
      int row  = it * 16 + rloc;
      int grow = t0 + row;
      float v[8];
      if (grow < LSEQ) {
        const float4* p = (const float4*)(xb + (long)grow * CIN + g * 8);
        float4 a0 = p[0], a1 = p[1];
        v[0]=a0.x; v[1]=a0.y; v[2]=a0.z; v[3]=a0.w;
        v[4]=a1.x; v[5]=a1.y; v[6]=a1.z; v[7]=a1.w;
      } else {
        #pragma unroll
        for (int j = 0; j < 8; ++j) v[j] = 0.f;
      }
      float s = 0.f;
      union { unsigned short us[8]; int4 q; } pk;
      #pragma unroll
      for (int j = 0; j < 8; ++j) {
        s += v[j] * v[j];
        __hip_bfloat16 hb = __float2bfloat16(v[j]);
        pk.us[j] = *reinterpret_cast<unsigned short*>(&hb);
      }
      int slot = (g & 8) | ((g ^ row) & 7);
      *(int4*)(Xs + row * 256 + slot * 16) = pk.q;
      // reduce s over the 16 loader lanes of this row
      s += __shfl_xor(s, 1, 16);
      s += __shfl_xor(s, 2, 16);
      s += __shfl_xor(s, 4, 16);
      s += __shfl_xor(s, 8, 16);
      if (g == 0) sqs[row] = s;
    }
  }
  __syncthreads();   // X + sqs ready, stage(0) drained; vmcnt=0 at loop entry

  // ---- window norm: rns[t] = scale / sqrt(sum_{k<15} sqs[t+k] + eps)
  if (tx < BM) {
    float wsum = 0.f;
    #pragma unroll
    for (int k = 0; k < K_TAPS; ++k) wsum += sqs[tx + k];
    rns[tx] = scalev / sqrtf(wsum + 1e-7f);
  }

  f32x4 acc[4][4] = {};   // [m][n], accumulate across ALL phases

  const int klane = lane >> 4;
  const int rl    = lane & 15;
  const int arow0 = wm * 64;
  const int bcol0 = wn * 64;

  #pragma unroll 2
  for (int ph = 0; ph < NPHASE; ++ph) {
    const int buf = ph & 1;
    const int tap = ph >> 1;
    const int kk0 = (ph & 1) * 2;

    // issue next-phase B prefetch (stays in flight across the barrier)
    if (ph + 1 < NPHASE) stageB(buf ^ 1, ph + 1);

    // hoist A ds_reads -- Xs is immutable, no barrier needed
    bf16x8 af[2][4];
    #pragma unroll
    for (int j = 0; j < 2; ++j) {
      const int ga = (kk0 + j) * 4 + klane;   // A granule 0..15
      #pragma unroll
      for (int mf = 0; mf < 4; ++mf) {
        int row  = arow0 + mf * 16 + rl + tap;
        int slot = (ga & 8) | ((ga ^ row) & 7);
        af[j][mf] = *(const bf16x8*)(Xs + row * 256 + slot * 16);
      }
    }

    // counted wait: drain only THIS phase's B loads, keep next 4 in flight
    if (ph + 1 < NPHASE) {
      asm volatile("s_waitcnt vmcnt(4)" ::: "memory");
    } else {
      asm volatile("s_waitcnt vmcnt(0)" ::: "memory");
    }
    __builtin_amdgcn_s_barrier();      // buf(ph) ready in all waves

    const char* Bsc = Bs + buf * BBYTES;
    bf16x8 bfr[2][4];
    #pragma unroll
    for (int j = 0; j < 2; ++j) {
      const int gb = ((kk0 + j) & 1) * 4 + klane;  // granule within half
      #pragma unroll
      for (int nf = 0; nf < 4; ++nf) {
        int fc   = bcol0 + nf * 16 + rl;
        int slot = (gb ^ fc) & 7;
        bfr[j][nf] = *(const bf16x8*)(Bsc + fc * 128 + slot * 16);
      }
    }

    __builtin_amdgcn_s_setprio(1);
    #pragma unroll
    for (int j = 0; j < 2; ++j)
      #pragma unroll
      for (int mf = 0; mf < 4; ++mf)
        #pragma unroll
        for (int nf = 0; nf < 4; ++nf)
          acc[mf][nf] = __builtin_amdgcn_mfma_f32_16x16x32_bf16(
              af[j][mf], bfr[j][nf], acc[mf][nf], 0, 0, 0);
    __builtin_amdgcn_s_setprio(0);

    // buf's ds_reads complete before next phase's stage may overwrite it
    asm volatile("s_waitcnt lgkmcnt(0)" ::: "memory");
    __builtin_amdgcn_s_barrier();
  }

  // ---- epilogue: out = acc * rns[row] + bias[f]
  // C/D layout: col = lane&15, row = (lane>>4)*4 + reg  [m89-verified]
  const int rgrp = lane >> 4;
  float biasv[4];
  #pragma unroll
  for (int nf = 0; nf < 4; ++nf) biasv[nf] = bias[n0 + bcol0 + nf * 16 + rl];
  float* ob = out + (long)b * LOUT * F_OUT;
  #pragma unroll
  for (int mf = 0; mf < 4; ++mf) {
    #pragma unroll
    for (int r = 0; r < 4; ++r) {
      int row = arow0 + mf * 16 + rgrp * 4 + r;
      int gt  = t0 + row;
      if (gt < LOUT) {
        float rv = rns[row];
        #pragma unroll
        for (int nf = 0; nf < 4; ++nf) {
          ob[(long)gt * F_OUT + n0 + bcol0 + nf * 16 + rl] =
              acc[mf][nf][r] * rv + biasv[nf];
        }
      }
    }
  }
}

// ---------------------------------------------------------------------------
extern "C" void kernel_launch(void* const* d_in, const int* in_sizes, int n_in,
                              void* d_out, int out_size, void* d_ws, size_t ws_size,
                              hipStream_t stream) {
  const float* x     = (const float*)d_in[0];   // (32, 4096, 128)
  const float* W     = (const float*)d_in[1];   // (15, 128, 256)
  const float* scale = (const float*)d_in[2];   // (1,1,1)
  const float* bias  = (const float*)d_in[3];   // (256,)
  float* out = (float*)d_out;                   // (32, 4082, 256)

  unsigned short* Wp = (unsigned short*)d_ws;   // 983040 B

  prep_w_kernel<<<1920, 256, 0, stream>>>(W, Wp);
  conv_gemm_kernel<<<dim3(64, BATCH), 256, 0, stream>>>(x, Wp, scale, bias, out);
}

// Round 8
// 148.063 us; speedup vs baseline: 1.2456x; 1.0502x over previous
//
#include <hip/hip_runtime.h>
#include <hip/hip_bf16.h>
#include <stdint.h>

#define K_TAPS 15
#define CIN    128
#define F_OUT  256
#define LSEQ   4096
#define LOUT   (LSEQ - K_TAPS + 1)   // 4082
#define BATCH  32

typedef __attribute__((ext_vector_type(8))) short bf16x8;
typedef __attribute__((ext_vector_type(4))) float f32x4;

typedef __attribute__((address_space(1))) const unsigned int gu32_t;
typedef __attribute__((address_space(3))) unsigned int su32_t;

// ---------------------------------------------------------------------------
// prep: weights fp32 [k][c][f] -> bf16 Wp, layout [(k*2+chalf)][f][64 ch swz]
// swizzle: within a 64-chan half, granule g=c6>>3 stored at slot g^(f&7)
// (R3-verified layout -- staging src contiguous, LDS dest linear)
// ---------------------------------------------------------------------------
__global__ void prep_w_kernel(const float* __restrict__ W,
                              unsigned short* __restrict__ Wp) {
  int idx = blockIdx.x * 256 + threadIdx.x;   // 15*128*256 = 491520 total
  int f  = idx & 255;
  int kc = idx >> 8;
  int c  = kc & 127;
  int k  = kc >> 7;
  float w = W[idx];
  __hip_bfloat16 hb = __float2bfloat16(w);
  int chalf = c >> 6;
  int c6    = c & 63;
  int slot  = ((c6 >> 3) ^ f) & 7;
  int cp    = slot * 8 + (c & 7);
  Wp[((size_t)(k * 2 + chalf) * 256 + f) * 64 + cp] =
      *reinterpret_cast<unsigned short*>(&hb);
}

// ---------------------------------------------------------------------------
// sq[b*4096+l] = sum_c x[b][l][c]^2   (exact fp32) -- kept SEPARATE (R7
// showed fusing this into conv perturbs main-loop codegen, -30%)
// ---------------------------------------------------------------------------
__global__ void sq_kernel(const float* __restrict__ x, float* __restrict__ sq) {
  int wid  = threadIdx.x >> 6;
  int lane = threadIdx.x & 63;
  int half = lane >> 5;
  int lq   = lane & 31;
  long pos = (long)blockIdx.x * 8 + wid * 2 + half;   // < 32*4096
  const float4* xp = (const float4*)(x + pos * CIN) + lq;
  float4 v = *xp;
  float s = v.x * v.x + v.y * v.y + v.z * v.z + v.w * v.w;
  #pragma unroll
  for (int m = 1; m <= 16; m <<= 1) s += __shfl_xor(s, m, 64);
  if (lq == 0) sq[pos] = s;
}

// ---------------------------------------------------------------------------
// rn[b*4096+t] = scale / sqrt( sum_{k<15} sq[b][t+k] + 1e-7 )
// ---------------------------------------------------------------------------
__global__ void rn_kernel(const float* __restrict__ sq,
                          const float* __restrict__ scale,
                          float* __restrict__ rn) {
  int t = blockIdx.x * 256 + threadIdx.x;
  int b = blockIdx.y;
  if (t >= LOUT) return;
  const float* s = sq + b * LSEQ + t;
  float w = 0.f;
  #pragma unroll
  for (int k = 0; k < K_TAPS; ++k) w += s[k];
  rn[b * LSEQ + t] = scale[0] / sqrtf(w + 1e-7f);
}

// ---------------------------------------------------------------------------
// main implicit-GEMM conv -- m201-style 8-phase schedule on a 256x256 tile
// block: 512 thr = 8 waves, wave grid 2(M)x4(N), wave tile 128x64
// LDS: Xs [272 rows][128 ch] bf16, R3 XOR swizzle, staged once (135 KB tot)
//      Bs double buffer, each [256 f][64 ch swz] (global_load_lds, 16B)
// K loop: 30 half-tap steps x 4 sub-phases; each sub-phase = {4-8 ds_read
//   (+ stage issue at sub-phase 0) -> barrier -> lgkmcnt(0) -> setprio(1)
//   16 MFMA setprio(0) -> barrier}; single vmcnt(0) per step, 3 sub-phases
//   after issue (never mid-phase).  reads/MFMA = 24/64 = 0.375 -> MFMA-bound
// ---------------------------------------------------------------------------
#define BM 256
#define BN 256
#define XROWS 272              // 256 + 15 halo, padded to 16
#define XBYTES (XROWS * 256)   // 69632
#define BBYTES 32768           // one [256][64] bf16 buffer
#define NSTEP (K_TAPS * 2)     // 30

__global__ __launch_bounds__(512, 2) void conv_gemm_kernel(
    const float* __restrict__ x, const unsigned short* __restrict__ Wp,
    const float* __restrict__ rn, const float* __restrict__ bias,
    float* __restrict__ out)
{
  __shared__ __align__(16) char lds[XBYTES + 2 * BBYTES];  // 135168 B
  char* Xs = lds;
  char* Bs = lds + XBYTES;

  const int b  = blockIdx.y;
  const int t0 = blockIdx.x * BM;

  const int tx   = threadIdx.x;
  const int wid  = tx >> 6;
  const int lane = tx & 63;
  const int wm   = wid >> 2;     // 0..1
  const int wn   = wid & 3;      // 0..3

  const int klane = lane >> 4;
  const int rl    = lane & 15;
  const int arow0 = wm * 128;
  const int bcol0 = wn * 64;

  // ---- B staging: one 32 KB half-tap image (all 256 f), linear copy
  auto stageB = [&](int buf, int step) {
    const char* src = (const char*)Wp + (size_t)step * 32768;
    char* dst = Bs + buf * BBYTES;
    #pragma unroll
    for (int i = 0; i < 4; ++i) {
      int off = i * 8192 + wid * 1024;   // wave-uniform base
      __builtin_amdgcn_global_load_lds(
          (gu32_t*)(src + off + lane * 16),
          (su32_t*)(dst + off), 16, 0, 0);
    }
  };

  stageB(0, 0);   // drained by __syncthreads below

  // ---- stage X once: 272 rows x 128 ch, fp32 -> bf16, XOR-swizzled
  {
    const int rloc = tx >> 4;    // 0..31, row within 32-row slab
    const int g    = tx & 15;    // 16B granule (8 chans)
    const float* xb = x + (long)b * LSEQ * CIN;
    #pragma unroll
    for (int it = 0; it < 9; ++it) {
      int row  = it * 32 + rloc;          // 0..287
      int grow = t0 + row;
      if (row < XROWS) {
        float v[8];
        if (grow < LSEQ) {
          const float4* p = (const float4*)(xb + (long)grow * CIN + g * 8);
          float4 a0 = p[0], a1 = p[1];
          v[0]=a0.x; v[1]=a0.y; v[2]=a0.z; v[3]=a0.w;
          v[4]=a1.x; v[5]=a1.y; v[6]=a1.z; v[7]=a1.w;
        } else {
          #pragma unroll
          for (int j = 0; j < 8; ++j) v[j] = 0.f;
        }
        union { unsigned short us[8]; int4 q; } pk;
        #pragma unroll
        for (int j = 0; j < 8; ++j) {
          __hip_bfloat16 hb = __float2bfloat16(v[j]);
          pk.us[j] = *reinterpret_cast<unsigned short*>(&hb);
        }
        int slot = (g & 8) | ((g ^ row) & 7);
        *(int4*)(Xs + row * 256 + slot * 16) = pk.q;
      }
    }
  }
  __syncthreads();   // X ready, stage(0) drained; vmcnt=0 at loop entry

  f32x4 acc[8][4] = {};   // [mf][nf], wave tile 128x64

  #pragma unroll 2
  for (int s = 0; s < NSTEP; ++s) {
    const int tap = s >> 1;
    const int ch8 = (s & 1) * 8;             // granule base of this half-tap
    const char* Bsc = Bs + (s & 1) * BBYTES;

    bf16x8 afA[4], afB[4], bfr0[4], bfr1[4];

    // ===== sub-phase 0: A[kk0][mf0-3] + B[kk0] + stage(s+1) ================
    {
      const int ga = ch8 + klane;
      #pragma unroll
      for (int i = 0; i < 4; ++i) {
        int row  = arow0 + i * 16 + rl + tap;
        int slot = (ga & 8) | ((ga ^ row) & 7);
        afA[i] = *(const bf16x8*)(Xs + row * 256 + slot * 16);
      }
      #pragma unroll
      for (int nf = 0; nf < 4; ++nf) {
        int fc   = bcol0 + nf * 16 + rl;
        int slot = (klane ^ fc) & 7;         // gb = klane
        bfr0[nf] = *(const bf16x8*)(Bsc + fc * 128 + slot * 16);
      }
      if (s + 1 < NSTEP) stageB((s & 1) ^ 1, s + 1);
    }
    __builtin_amdgcn_s_barrier();
    asm volatile("s_waitcnt lgkmcnt(0)" ::: "memory");
    __builtin_amdgcn_s_setprio(1);
    #pragma unroll
    for (int i = 0; i < 4; ++i)
      #pragma unroll
      for (int nf = 0; nf < 4; ++nf)
        acc[i][nf] = __builtin_amdgcn_mfma_f32_16x16x32_bf16(
            afA[i], bfr0[nf], acc[i][nf], 0, 0, 0);
    __builtin_amdgcn_s_setprio(0);
    __builtin_amdgcn_s_barrier();

    // ===== sub-phase 1: A[kk0][mf4-7] ======================================
    {
      const int ga = ch8 + klane;
      #pragma unroll
      for (int i = 0; i < 4; ++i) {
        int row  = arow0 + (i + 4) * 16 + rl + tap;
        int slot = (ga & 8) | ((ga ^ row) & 7);
        afB[i] = *(const bf16x8*)(Xs + row * 256 + slot * 16);
      }
    }
    __builtin_amdgcn_s_barrier();
    asm volatile("s_waitcnt lgkmcnt(0)" ::: "memory");
    __builtin_amdgcn_s_setprio(1);
    #pragma unroll
    for (int i = 0; i < 4; ++i)
      #pragma unroll
      for (int nf = 0; nf < 4; ++nf)
        acc[i + 4][nf] = __builtin_amdgcn_mfma_f32_16x16x32_bf16(
            afB[i], bfr0[nf], acc[i + 4][nf], 0, 0, 0);
    __builtin_amdgcn_s_setprio(0);
    __builtin_amdgcn_s_barrier();

    // ===== sub-phase 2: A[kk1][mf0-3] + B[kk1] =============================
    {
      const int ga = ch8 + 4 + klane;
      const int gb = 4 + klane;
      #pragma unroll
      for (int i = 0; i < 4; ++i) {
        int row  = arow0 + i * 16 + rl + tap;
        int slot = (ga & 8) | ((ga ^ row) & 7);
        afA[i] = *(const bf16x8*)(Xs + row * 256 + slot * 16);
      }
      #pragma unroll
      for (int nf = 0; nf < 4; ++nf) {
        int fc   = bcol0 + nf * 16 + rl;
        int slot = (gb ^ fc) & 7;
        bfr1[nf] = *(const bf16x8*)(Bsc + fc * 128 + slot * 16);
      }
    }
    __builtin_amdgcn_s_barrier();
    asm volatile("s_waitcnt lgkmcnt(0)" ::: "memory");
    __builtin_amdgcn_s_setprio(1);
    #pragma unroll
    for (int i = 0; i < 4; ++i)
      #pragma unroll
      for (int nf = 0; nf < 4; ++nf)
        acc[i][nf] = __builtin_amdgcn_mfma_f32_16x16x32_bf16(
            afA[i], bfr1[nf], acc[i][nf], 0, 0, 0);
    __builtin_amdgcn_s_setprio(0);
    __builtin_amdgcn_s_barrier();

    // ===== sub-phase 3: A[kk1][mf4-7]; step-final vmcnt(0) =================
    {
      const int ga = ch8 + 4 + klane;
      #pragma unroll
      for (int i = 0; i < 4; ++i) {
        int row  = arow0 + (i + 4) * 16 + rl + tap;
        int slot = (ga & 8) | ((ga ^ row) & 7);
        afB[i] = *(const bf16x8*)(Xs + row * 256 + slot * 16);
      }
    }
    __builtin_amdgcn_s_barrier();
    asm volatile("s_waitcnt lgkmcnt(0)" ::: "memory");
    __builtin_amdgcn_s_setprio(1);
    #pragma unroll
    for (int i = 0; i < 4; ++i)
      #pragma unroll
      for (int nf = 0; nf < 4; ++nf)
        acc[i + 4][nf] = __builtin_amdgcn_mfma_f32_16x16x32_bf16(
            afB[i], bfr0 == bfr1 ? bfr1[nf] : bfr1[nf], acc[i + 4][nf], 0, 0, 0);
    __builtin_amdgcn_s_setprio(0);
    // drain this step's stage(s+1) loads (issued 3 sub-phases ago) so every
    // wave may read buf^1 after the barrier  [cross-wave: own vmcnt + barrier]
    asm volatile("s_waitcnt vmcnt(0)" ::: "memory");
    __builtin_amdgcn_s_barrier();
  }

  // ---- epilogue: out = acc * rn[row] + bias[f]
  // C/D layout: col = lane&15, row = (lane>>4)*4 + reg  [m89-verified]
  const int rgrp = lane >> 4;
  float biasv[4];
  #pragma unroll
  for (int nf = 0; nf < 4; ++nf) biasv[nf] = bias[bcol0 + nf * 16 + rl];
  float* ob = out + (long)b * LOUT * F_OUT;
  const float* rnb = rn + b * LSEQ + t0;
  #pragma unroll
  for (int mf = 0; mf < 8; ++mf) {
    #pragma unroll
    for (int r = 0; r < 4; ++r) {
      int row = arow0 + mf * 16 + rgrp * 4 + r;
      int gt  = t0 + row;
      if (gt < LOUT) {
        float rv = rnb[row];
        #pragma unroll
        for (int nf = 0; nf < 4; ++nf) {
          ob[(long)gt * F_OUT + bcol0 + nf * 16 + rl] =
              acc[mf][nf][r] * rv + biasv[nf];
        }
      }
    }
  }
}

// ---------------------------------------------------------------------------
extern "C" void kernel_launch(void* const* d_in, const int* in_sizes, int n_in,
                              void* d_out, int out_size, void* d_ws, size_t ws_size,
                              hipStream_t stream) {
  const float* x     = (const float*)d_in[0];   // (32, 4096, 128)
  const float* W     = (const float*)d_in[1];   // (15, 128, 256)
  const float* scale = (const float*)d_in[2];   // (1,1,1)
  const float* bias  = (const float*)d_in[3];   // (256,)
  float* out = (float*)d_out;                   // (32, 4082, 256)

  char* ws = (char*)d_ws;
  unsigned short* Wp = (unsigned short*)ws;                  // 983040 B
  float* sq = (float*)(ws + 1048576);                        // 524288 B
  float* rn = (float*)(ws + 1048576 + 524288);               // 524288 B

  prep_w_kernel<<<1920, 256, 0, stream>>>(W, Wp);
  sq_kernel<<<BATCH * LSEQ / 8, 256, 0, stream>>>(x, sq);
  rn_kernel<<<dim3((LOUT + 255) / 256, BATCH), 256, 0, stream>>>(sq, scale, rn);
  conv_gemm_kernel<<<dim3(16, BATCH), 512, 0, stream>>>(x, Wp, rn, bias, out);
}

// Round 9
// 147.010 us; speedup vs baseline: 1.2545x; 1.0072x over previous
//
#include <hip/hip_runtime.h>
#include <hip/hip_bf16.h>
#include <stdint.h>

#define K_TAPS 15
#define CIN    128
#define F_OUT  256
#define LSEQ   4096
#define LOUT   (LSEQ - K_TAPS + 1)   // 4082
#define BATCH  32

typedef __attribute__((ext_vector_type(8))) short bf16x8;
typedef __attribute__((ext_vector_type(4))) float f32x4;

typedef __attribute__((address_space(1))) const unsigned int gu32_t;
typedef __attribute__((address_space(3))) unsigned int su32_t;

// ---------------------------------------------------------------------------
// prep: weights fp32 [k][c][f] -> bf16 Wp, layout [(k*2+chalf)][f][64 ch swz]
// swizzle: within a 64-chan half, granule g=c6>>3 stored at slot g^(f&7)
// ---------------------------------------------------------------------------
__global__ void prep_w_kernel(const float* __restrict__ W,
                              unsigned short* __restrict__ Wp) {
  int idx = blockIdx.x * 256 + threadIdx.x;   // 15*128*256 = 491520 total
  int f  = idx & 255;
  int kc = idx >> 8;
  int c  = kc & 127;
  int k  = kc >> 7;
  float w = W[idx];
  __hip_bfloat16 hb = __float2bfloat16(w);
  int chalf = c >> 6;
  int c6    = c & 63;
  int slot  = ((c6 >> 3) ^ f) & 7;
  int cp    = slot * 8 + (c & 7);
  Wp[((size_t)(k * 2 + chalf) * 256 + f) * 64 + cp] =
      *reinterpret_cast<unsigned short*>(&hb);
}

// ---------------------------------------------------------------------------
// sq[b*4096+l] = sum_c x[b][l][c]^2   (exact fp32) -- separate (R7: fusion
// into conv perturbs main-loop codegen, -30%)
// ---------------------------------------------------------------------------
__global__ void sq_kernel(const float* __restrict__ x, float* __restrict__ sq) {
  int wid  = threadIdx.x >> 6;
  int lane = threadIdx.x & 63;
  int half = lane >> 5;
  int lq   = lane & 31;
  long pos = (long)blockIdx.x * 8 + wid * 2 + half;   // < 32*4096
  const float4* xp = (const float4*)(x + pos * CIN) + lq;
  float4 v = *xp;
  float s = v.x * v.x + v.y * v.y + v.z * v.z + v.w * v.w;
  #pragma unroll
  for (int m = 1; m <= 16; m <<= 1) s += __shfl_xor(s, m, 64);
  if (lq == 0) sq[pos] = s;
}

// ---------------------------------------------------------------------------
// rn[b*4096+t] = scale / sqrt( sum_{k<15} sq[b][t+k] + 1e-7 )
// ---------------------------------------------------------------------------
__global__ void rn_kernel(const float* __restrict__ sq,
                          const float* __restrict__ scale,
                          float* __restrict__ rn) {
  int t = blockIdx.x * 256 + threadIdx.x;
  int b = blockIdx.y;
  if (t >= LOUT) return;
  const float* s = sq + b * LSEQ + t;
  float w = 0.f;
  #pragma unroll
  for (int k = 0; k < K_TAPS; ++k) w += s[k];
  rn[b * LSEQ + t] = scale[0] / sqrtf(w + 1e-7f);
}

// ---------------------------------------------------------------------------
// main implicit-GEMM conv -- 256x256 tile, 4 sub-phases/step, T4 counted vmcnt
// block: 512 thr = 8 waves, wave grid 2(M)x4(N), wave tile 128x64
// LDS: Xs [272 rows][128 ch] bf16, R3 XOR swizzle, staged once
//      Bs double buffer, each [256 f][64 ch swz]; stage split in 16KB halves
//      issued at sub-phases 0 and 2, drained by vmcnt(4) one step later
//      (never 0 in the main loop -- m218: counted-vs-drain0 is T3's gain)
// ---------------------------------------------------------------------------
#define BM 256
#define BN 256
#define XROWS 272              // 256 + 15 halo, padded to 16
#define XBYTES (XROWS * 256)   // 69632
#define BBYTES 32768           // one [256][64] bf16 buffer
#define NSTEP (K_TAPS * 2)     // 30

__global__ __launch_bounds__(512, 2) void conv_gemm_kernel(
    const float* __restrict__ x, const unsigned short* __restrict__ Wp,
    const float* __restrict__ rn, const float* __restrict__ bias,
    float* __restrict__ out)
{
  __shared__ __align__(16) char lds[XBYTES + 2 * BBYTES];  // 135168 B
  char* Xs = lds;
  char* Bs = lds + XBYTES;

  const int b  = blockIdx.y;
  const int t0 = blockIdx.x * BM;

  const int tx   = threadIdx.x;
  const int wid  = tx >> 6;
  const int lane = tx & 63;
  const int wm   = wid >> 2;     // 0..1
  const int wn   = wid & 3;      // 0..3

  const int klane = lane >> 4;
  const int rl    = lane & 15;
  const int arow0 = wm * 128;
  const int bcol0 = wn * 64;

  // ---- B staging: 16 KB half of a half-tap image (128 f), linear copy
  auto stageB2 = [&](int buf, int step, int half) {
    const char* src = (const char*)Wp + (size_t)step * 32768 + half * 16384;
    char* dst = Bs + buf * BBYTES + half * 16384;
    #pragma unroll
    for (int i = 0; i < 2; ++i) {
      int off = i * 8192 + wid * 1024;   // wave-uniform base
      __builtin_amdgcn_global_load_lds(
          (gu32_t*)(src + off + lane * 16),
          (su32_t*)(dst + off), 16, 0, 0);
    }
  };

  stageB2(0, 0, 0);
  stageB2(0, 0, 1);   // drained by __syncthreads below

  // ---- stage X once: 272 rows x 128 ch, fp32 -> bf16, XOR-swizzled
  {
    const int rloc = tx >> 4;    // 0..31, row within 32-row slab
    const int g    = tx & 15;    // 16B granule (8 chans)
    const float* xb = x + (long)b * LSEQ * CIN;
    #pragma unroll
    for (int it = 0; it < 9; ++it) {
      int row  = it * 32 + rloc;          // 0..287
      int grow = t0 + row;
      if (row < XROWS) {
        float v[8];
        if (grow < LSEQ) {
          const float4* p = (const float4*)(xb + (long)grow * CIN + g * 8);
          float4 a0 = p[0], a1 = p[1];
          v[0]=a0.x; v[1]=a0.y; v[2]=a0.z; v[3]=a0.w;
          v[4]=a1.x; v[5]=a1.y; v[6]=a1.z; v[7]=a1.w;
        } else {
          #pragma unroll
          for (int j = 0; j < 8; ++j) v[j] = 0.f;
        }
        union { unsigned short us[8]; int4 q; } pk;
        #pragma unroll
        for (int j = 0; j < 8; ++j) {
          __hip_bfloat16 hb = __float2bfloat16(v[j]);
          pk.us[j] = *reinterpret_cast<unsigned short*>(&hb);
        }
        int slot = (g & 8) | ((g ^ row) & 7);
        *(int4*)(Xs + row * 256 + slot * 16) = pk.q;
      }
    }
  }
  __syncthreads();   // X ready, stage(0) drained; vmcnt=0 at loop entry

  f32x4 acc[8][4] = {};   // [mf][nf], wave tile 128x64

  #pragma unroll 2
  for (int s = 0; s < NSTEP; ++s) {
    const int tap = s >> 1;
    const int ch8 = (s & 1) * 8;             // granule base of this half-tap
    const int cur = s & 1;
    const char* Bsc = Bs + cur * BBYTES;

    bf16x8 afA[4], afB[4], bfr0[4], bfr1[4];

    // ===== sub-phase 0: A[kk0][mf0-3]; stage h0(s+1); vmcnt(4) -> B[kk0] ===
    {
      const int ga = ch8 + klane;
      #pragma unroll
      for (int i = 0; i < 4; ++i) {
        int row  = arow0 + i * 16 + rl + tap;
        int slot = (ga & 8) | ((ga ^ row) & 7);
        afA[i] = *(const bf16x8*)(Xs + row * 256 + slot * 16);
      }
    }
    if (s + 1 < NSTEP) {
      stageB2(cur ^ 1, s + 1, 0);
      asm volatile("s_waitcnt vmcnt(4)" ::: "memory");  // h0(s) landed
    } else {
      asm volatile("s_waitcnt vmcnt(2)" ::: "memory");  // h0(s) landed
    }
    __builtin_amdgcn_s_barrier();            // all waves' h0(s) landed
    {
      #pragma unroll
      for (int nf = 0; nf < 4; ++nf) {
        int fc   = bcol0 + nf * 16 + rl;
        int slot = (klane ^ fc) & 7;         // gb = klane
        bfr0[nf] = *(const bf16x8*)(Bsc + fc * 128 + slot * 16);
      }
    }
    asm volatile("s_waitcnt lgkmcnt(0)" ::: "memory");
    __builtin_amdgcn_s_setprio(1);
    #pragma unroll
    for (int i = 0; i < 4; ++i)
      #pragma unroll
      for (int nf = 0; nf < 4; ++nf)
        acc[i][nf] = __builtin_amdgcn_mfma_f32_16x16x32_bf16(
            afA[i], bfr0[nf], acc[i][nf], 0, 0, 0);
    __builtin_amdgcn_s_setprio(0);
    __builtin_amdgcn_s_barrier();

    // ===== sub-phase 1: A[kk0][mf4-7] ======================================
    {
      const int ga = ch8 + klane;
      #pragma unroll
      for (int i = 0; i < 4; ++i) {
        int row  = arow0 + (i + 4) * 16 + rl + tap;
        int slot = (ga & 8) | ((ga ^ row) & 7);
        afB[i] = *(const bf16x8*)(Xs + row * 256 + slot * 16);
      }
    }
    __builtin_amdgcn_s_barrier();
    asm volatile("s_waitcnt lgkmcnt(0)" ::: "memory");
    __builtin_amdgcn_s_setprio(1);
    #pragma unroll
    for (int i = 0; i < 4; ++i)
      #pragma unroll
      for (int nf = 0; nf < 4; ++nf)
        acc[i + 4][nf] = __builtin_amdgcn_mfma_f32_16x16x32_bf16(
            afB[i], bfr0[nf], acc[i + 4][nf], 0, 0, 0);
    __builtin_amdgcn_s_setprio(0);
    __builtin_amdgcn_s_barrier();

    // ===== sub-phase 2: A[kk1][mf0-3]; stage h1(s+1); vmcnt(4) -> B[kk1] ===
    {
      const int ga = ch8 + 4 + klane;
      #pragma unroll
      for (int i = 0; i < 4; ++i) {
        int row  = arow0 + i * 16 + rl + tap;
        int slot = (ga & 8) | ((ga ^ row) & 7);
        afA[i] = *(const bf16x8*)(Xs + row * 256 + slot * 16);
      }
    }
    if (s + 1 < NSTEP) {
      stageB2(cur ^ 1, s + 1, 1);
      asm volatile("s_waitcnt vmcnt(4)" ::: "memory");  // h1(s) landed
    } else {
      asm volatile("s_waitcnt vmcnt(0)" ::: "memory");  // h1(s) landed
    }
    __builtin_amdgcn_s_barrier();            // all waves' h1(s) landed
    {
      const int gb = 4 + klane;
      #pragma unroll
      for (int nf = 0; nf < 4; ++nf) {
        int fc   = bcol0 + nf * 16 + rl;
        int slot = (gb ^ fc) & 7;
        bfr1[nf] = *(const bf16x8*)(Bsc + fc * 128 + slot * 16);
      }
    }
    asm volatile("s_waitcnt lgkmcnt(0)" ::: "memory");
    __builtin_amdgcn_s_setprio(1);
    #pragma unroll
    for (int i = 0; i < 4; ++i)
      #pragma unroll
      for (int nf = 0; nf < 4; ++nf)
        acc[i][nf] = __builtin_amdgcn_mfma_f32_16x16x32_bf16(
            afA[i], bfr1[nf], acc[i][nf], 0, 0, 0);
    __builtin_amdgcn_s_setprio(0);
    __builtin_amdgcn_s_barrier();

    // ===== sub-phase 3: A[kk1][mf4-7] ======================================
    {
      const int ga = ch8 + 4 + klane;
      #pragma unroll
      for (int i = 0; i < 4; ++i) {
        int row  = arow0 + (i + 4) * 16 + rl + tap;
        int slot = (ga & 8) | ((ga ^ row) & 7);
        afB[i] = *(const bf16x8*)(Xs + row * 256 + slot * 16);
      }
    }
    __builtin_amdgcn_s_barrier();
    asm volatile("s_waitcnt lgkmcnt(0)" ::: "memory");
    __builtin_amdgcn_s_setprio(1);
    #pragma unroll
    for (int i = 0; i < 4; ++i)
      #pragma unroll
      for (int nf = 0; nf < 4; ++nf)
        acc[i + 4][nf] = __builtin_amdgcn_mfma_f32_16x16x32_bf16(
            afB[i], bfr1[nf], acc[i + 4][nf], 0, 0, 0);
    __builtin_amdgcn_s_setprio(0);
    __builtin_amdgcn_s_barrier();
  }

  // ---- epilogue: out = acc * rn[row] + bias[f]
  // C/D layout: col = lane&15, row = (lane>>4)*4 + reg  [m89-verified]
  const int rgrp = lane >> 4;
  float biasv[4];
  #pragma unroll
  for (int nf = 0; nf < 4; ++nf) biasv[nf] = bias[bcol0 + nf * 16 + rl];
  float* ob = out + (long)b * LOUT * F_OUT;
  const float* rnb = rn + b * LSEQ + t0;
  #pragma unroll
  for (int mf = 0; mf < 8; ++mf) {
    #pragma unroll
    for (int r = 0; r < 4; ++r) {
      int row = arow0 + mf * 16 + rgrp * 4 + r;
      int gt  = t0 + row;
      if (gt < LOUT) {
        float rv = rnb[row];
        #pragma unroll
        for (int nf = 0; nf < 4; ++nf) {
          ob[(long)gt * F_OUT + bcol0 + nf * 16 + rl] =
              acc[mf][nf][r] * rv + biasv[nf];
        }
      }
    }
  }
}

// ---------------------------------------------------------------------------
extern "C" void kernel_launch(void* const* d_in, const int* in_sizes, int n_in,
                              void* d_out, int out_size, void* d_ws, size_t ws_size,
                              hipStream_t stream) {
  const float* x     = (const float*)d_in[0];   // (32, 4096, 128)
  const float* W     = (const float*)d_in[1];   // (15, 128, 256)
  const float* scale = (const float*)d_in[2];   // (1,1,1)
  const float* bias  = (const float*)d_in[3];   // (256,)
  float* out = (float*)d_out;                   // (32, 4082, 256)

  char* ws = (char*)d_ws;
  unsigned short* Wp = (unsigned short*)ws;                  // 983040 B
  float* sq = (float*)(ws + 1048576);                        // 524288 B
  float* rn = (float*)(ws + 1048576 + 524288);               // 524288 B

  prep_w_kernel<<<1920, 256, 0, stream>>>(W, Wp);
  sq_kernel<<<BATCH * LSEQ / 8, 256, 0, stream>>>(x, sq);
  rn_kernel<<<dim3((LOUT + 255) / 256, BATCH), 256, 0, stream>>>(sq, scale, rn);
  conv_gemm_kernel<<<dim3(16, BATCH), 512, 0, stream>>>(x, Wp, rn, bias, out);
}